// Round 4
// baseline (1386.040 us; speedup 1.0000x reference)
//
#include <hip/hip_runtime.h>
#include <math.h>

#define NNODES  200000
#define NEDGES  6400000
#define NGRAPHS 512
#define FIN     92
#define WID     10
#define HPAD    16                     // hs row padded to 16 floats (64 B)
#define NXCD    8
#define NV      (NXCD * NNODES)        // 1,600,000 scan elements
#define NBLK    ((NNODES + 255) / 256) // 782
#define VBLK    (NV / 256)             // 6250 (exact)
#define EBLK    (NEDGES / 256)         // 25000 (exact)

// Physical XCD id of the executing workgroup (0..7, measured on MI355X).
__device__ __forceinline__ int xcc_id() {
    unsigned x;
    asm volatile("s_getreg_b32 %0, hwreg(HW_REG_XCC_ID)" : "=s"(x));
    return (int)(x & (NXCD - 1));
}

// ---------------------------------------------------------------------------
// K1: per-XCD degree histograms with WORKGROUP-scope atomics (stay in the
// local XCD L2 -- no sc1 bypass, no HBM write-through). The indeg atomic's
// return value is this edge's rank within its (xcd,dst) cell; token = x|rank
// lets the fill kernel place edges with ZERO atomics.
//   C[x*N + n] = # edges with dst n processed by XCD x
//   O[x*N + n] = # edges with src n processed by XCD x
// ---------------------------------------------------------------------------
__global__ void k_hist(const int* __restrict__ src,
                       const int* __restrict__ dst,
                       unsigned* __restrict__ C,
                       unsigned* __restrict__ O,
                       unsigned short* __restrict__ token) {
    int e = blockIdx.x * blockDim.x + threadIdx.x;
    int x = xcc_id();
    int s = src[e];
    int d = dst[e];
    __hip_atomic_fetch_add(&O[(size_t)x * NNODES + s], 1u,
                           __ATOMIC_RELAXED, __HIP_MEMORY_SCOPE_WORKGROUP);
    unsigned rank = __hip_atomic_fetch_add(&C[(size_t)x * NNODES + d], 1u,
                                           __ATOMIC_RELAXED, __HIP_MEMORY_SCOPE_WORKGROUP);
    token[e] = (unsigned short)((x << 12) | (rank & 0xFFFu));
}

// ---------------------------------------------------------------------------
// K2: per-block partial sums over the NV virtual elements v = n*8 + x
// (v-order makes each node's 8 per-XCD cells adjacent in the scan, so the
// CSR stays node-contiguous). Storage of C is x-major: idx = x*N + n.
// ---------------------------------------------------------------------------
__global__ void k_scan_partial(const unsigned* __restrict__ C,
                               int* __restrict__ partial) {
    __shared__ int sdata[256];
    int tid = threadIdx.x;
    int v = blockIdx.x * 256 + tid;           // v < NV (grid exact)
    int x = v & 7, n = v >> 3;
    sdata[tid] = (int)C[(size_t)x * NNODES + n];
    __syncthreads();
    for (int s = 128; s > 0; s >>= 1) {
        if (tid < s) sdata[tid] += sdata[tid + s];
        __syncthreads();
    }
    if (tid == 0) partial[blockIdx.x] = sdata[0];
}

// ---------------------------------------------------------------------------
// K3: single-block exclusive scan of the 6250 partials (chunked Hillis-Steele)
// ---------------------------------------------------------------------------
__global__ void k_scan_top(int* __restrict__ partial) {
    __shared__ int buf[1024];
    __shared__ int carry_s;
    if (threadIdx.x == 0) carry_s = 0;
    __syncthreads();
    for (int base = 0; base < VBLK; base += 1024) {
        int i = base + threadIdx.x;
        int c = carry_s;
        int orig = (i < VBLK) ? partial[i] : 0;
        buf[threadIdx.x] = orig;
        __syncthreads();
        for (int off = 1; off < 1024; off <<= 1) {
            int t = (threadIdx.x >= off) ? buf[threadIdx.x - off] : 0;
            __syncthreads();
            buf[threadIdx.x] += t;
            __syncthreads();
        }
        if (i < VBLK) partial[i] = buf[threadIdx.x] - orig + c;
        __syncthreads();
        if (threadIdx.x == 0) carry_s = c + buf[1023];
        __syncthreads();
    }
}

// ---------------------------------------------------------------------------
// K4: base offsets (exclusive scan, in place over C) + inv-sqrt degrees.
// All 8 cells of a node fall in one block (256 | 8). The x==0 plane of the
// scanned array, C[0..N), doubles as row_ptr (row end for last node = NEDGES).
// ---------------------------------------------------------------------------
__global__ void k_base(unsigned* __restrict__ C,       // counts -> base, in place
                       const unsigned* __restrict__ O,
                       const int* __restrict__ partial,
                       float* __restrict__ inv_in,
                       float* __restrict__ inv_out) {
    __shared__ int buf[256];
    __shared__ int raw[256];
    int tid = threadIdx.x;
    int v = blockIdx.x * 256 + tid;
    int x = v & 7, n = v >> 3;
    size_t idx = (size_t)x * NNODES + n;
    int c = (int)C[idx];
    raw[tid] = c;
    buf[tid] = c;
    __syncthreads();
    for (int off = 1; off < 256; off <<= 1) {
        int t = (tid >= off) ? buf[tid - off] : 0;
        __syncthreads();
        buf[tid] += t;
        __syncthreads();
    }
    C[idx] = (unsigned)(buf[tid] - c + partial[blockIdx.x]);
    if (x == 0) {
        int ind = 0;
#pragma unroll
        for (int k = 0; k < 8; k++) ind += raw[tid + k];
        unsigned od = 0;
#pragma unroll
        for (int k = 0; k < 8; k++) od += O[(size_t)k * NNODES + n];
        inv_in[n]  = rsqrtf((float)(ind < 1 ? 1 : ind));
        inv_out[n] = rsqrtf((float)(od  < 1u ? 1u : od));
    }
}

// ---------------------------------------------------------------------------
// K5: hs[n,:] = (A[n,:] @ W_emb + b_emb) * inv_sqrt_out[n], padded rows
// ---------------------------------------------------------------------------
__global__ void k_embed(const float* __restrict__ A,
                        const float* __restrict__ Wemb,
                        const float* __restrict__ bemb,
                        const float* __restrict__ inv_out,
                        float* __restrict__ hs) {
    __shared__ float sW[FIN * WID];
    __shared__ float sb[WID];
    for (int i = threadIdx.x; i < FIN * WID; i += blockDim.x) sW[i] = Wemb[i];
    if (threadIdx.x < WID) sb[threadIdx.x] = bemb[threadIdx.x];
    __syncthreads();

    int n = blockIdx.x * blockDim.x + threadIdx.x;
    if (n >= NNODES) return;

    float acc[WID];
#pragma unroll
    for (int k = 0; k < WID; k++) acc[k] = sb[k];

    const float4* row4 = reinterpret_cast<const float4*>(A + (size_t)n * FIN);
#pragma unroll
    for (int f4 = 0; f4 < FIN / 4; f4++) {
        float4 v = row4[f4];
        int f = f4 * 4;
#pragma unroll
        for (int k = 0; k < WID; k++) acc[k] += v.x * sW[(f + 0) * WID + k];
#pragma unroll
        for (int k = 0; k < WID; k++) acc[k] += v.y * sW[(f + 1) * WID + k];
#pragma unroll
        for (int k = 0; k < WID; k++) acc[k] += v.z * sW[(f + 2) * WID + k];
#pragma unroll
        for (int k = 0; k < WID; k++) acc[k] += v.w * sW[(f + 3) * WID + k];
    }

    float sc = inv_out[n];
    float* out = hs + (size_t)n * HPAD;
    float4 o0 = make_float4(acc[0] * sc, acc[1] * sc, acc[2] * sc, acc[3] * sc);
    float4 o1 = make_float4(acc[4] * sc, acc[5] * sc, acc[6] * sc, acc[7] * sc);
    float2 o2 = make_float2(acc[8] * sc, acc[9] * sc);
    *reinterpret_cast<float4*>(out + 0) = o0;
    *reinterpret_cast<float4*>(out + 4) = o1;
    *reinterpret_cast<float2*>(out + 8) = o2;
}

// ---------------------------------------------------------------------------
// K6: atomic-free CSR fill: pos = base[(x,dst)] + rank (from token)
// ---------------------------------------------------------------------------
__global__ void k_fill(const float* __restrict__ r,
                       const int* __restrict__ src,
                       const int* __restrict__ dst,
                       const unsigned short* __restrict__ token,
                       const unsigned* __restrict__ base,
                       float2* __restrict__ csr) {
    int e = blockIdx.x * blockDim.x + threadIdx.x;
    float x0 = r[3 * e + 0];
    float y  = r[3 * e + 1];
    float z  = r[3 * e + 2];
    float w = expf(-(x0 * x0 + y * y + z * z));
    int s = src[e];
    int d = dst[e];
    unsigned t = token[e];
    int xc = t >> 12;
    int rank = t & 0xFFF;
    unsigned pos = base[(size_t)xc * NNODES + d] + rank;
    csr[pos] = make_float2(w, __int_as_float(s));
}

// ---------------------------------------------------------------------------
// K7: pull-mode aggregate of gconv1 FUSED with node update + gconv2 proj.
// row_ptr == x==0 plane of base; row end for the last node is NEDGES.
// ---------------------------------------------------------------------------
__global__ void k_agg1(const float2* __restrict__ csr,
                       const unsigned* __restrict__ base,
                       const float* __restrict__ hs,
                       const float* __restrict__ W1,
                       const float* __restrict__ b1,
                       const float* __restrict__ W2,
                       const float* __restrict__ inv_in,
                       const float* __restrict__ inv_out,
                       float* __restrict__ sproj) {
    __shared__ float sW1[WID * WID];
    __shared__ float sb1[WID];
    __shared__ float sW2[WID];
    for (int i = threadIdx.x; i < WID * WID; i += blockDim.x) sW1[i] = W1[i];
    if (threadIdx.x < WID) {
        sb1[threadIdx.x] = b1[threadIdx.x];
        sW2[threadIdx.x] = W2[threadIdx.x];
    }
    __syncthreads();

    int n = blockIdx.x * blockDim.x + threadIdx.x;
    if (n >= NNODES) return;

    int start = (int)base[n];
    int end = (n == NNODES - 1) ? NEDGES : (int)base[n + 1];

    float acc[WID];
#pragma unroll
    for (int k = 0; k < WID; k++) acc[k] = 0.0f;

    for (int p = start; p < end; p++) {
        float2 c2 = csr[p];
        float w = c2.x;
        int s = __float_as_int(c2.y);
        const float* hrow = hs + (size_t)s * HPAD;
        float4 a = *reinterpret_cast<const float4*>(hrow + 0);
        float4 b = *reinterpret_cast<const float4*>(hrow + 4);
        float2 c = *reinterpret_cast<const float2*>(hrow + 8);
        acc[0] += w * a.x; acc[1] += w * a.y; acc[2] += w * a.z; acc[3] += w * a.w;
        acc[4] += w * b.x; acc[5] += w * b.y; acc[6] += w * b.z; acc[7] += w * b.w;
        acc[8] += w * c.x; acc[9] += w * c.y;
    }

    float ii = inv_in[n];
    float dot = 0.0f;
#pragma unroll
    for (int j = 0; j < WID; j++) {
        float y = 0.0f;
#pragma unroll
        for (int k = 0; k < WID; k++) y += acc[k] * sW1[k * WID + j];
        y = y * ii + sb1[j];
        y = y > 0.0f ? y : 0.0f;
        dot += y * sW2[j];
    }
    sproj[n] = dot * inv_out[n];
}

// ---------------------------------------------------------------------------
// K8: pull-mode scalar aggregate of gconv2 FUSED with graph pooling.
// NOTE: __shfl_down clamps out-of-range lanes to SELF on AMD -> guard with
// lane + off < 64 (round-2 bug).
// ---------------------------------------------------------------------------
__global__ void k_agg2_pool(const float2* __restrict__ csr,
                            const unsigned* __restrict__ base,
                            const float* __restrict__ sproj,
                            const float* __restrict__ inv_in,
                            const float* __restrict__ b2,
                            const int* __restrict__ graph_ids,
                            float* __restrict__ pooled) {
    int n = blockIdx.x * blockDim.x + threadIdx.x;
    int lane = threadIdx.x & 63;

    float v = 0.0f;
    int g = -1;
    if (n < NNODES) {
        int start = (int)base[n];
        int end = (n == NNODES - 1) ? NEDGES : (int)base[n + 1];
        float sum = 0.0f;
        for (int p = start; p < end; p++) {
            float2 c2 = csr[p];
            sum += c2.x * sproj[__float_as_int(c2.y)];
        }
        v = sum * inv_in[n] + b2[0];
        g = graph_ids[n];
    }

#pragma unroll
    for (int off = 1; off < 64; off <<= 1) {
        float vv = __shfl_down(v, off, 64);
        int gg = __shfl_down(g, off, 64);
        if (lane + off < 64 && gg == g) v += vv;
    }
    int gprev = __shfl_up(g, 1, 64);
    bool head = (lane == 0) || (gprev != g);
    if (g >= 0 && head) atomicAdd(&pooled[g], v);
}

// ---------------------------------------------------------------------------
// K9: out[g] = pooled[g] / count(g); counts via binary search on sorted gids
// ---------------------------------------------------------------------------
__global__ void k_final(const float* __restrict__ pooled,
                        const int* __restrict__ gids,
                        float* __restrict__ out) {
    int g = blockIdx.x * blockDim.x + threadIdx.x;
    if (g >= NGRAPHS) return;
    int lo = 0, hi = NNODES;
    while (lo < hi) { int m = (lo + hi) >> 1; if (gids[m] < g) lo = m + 1; else hi = m; }
    int first = lo;
    hi = NNODES;
    while (lo < hi) { int m = (lo + hi) >> 1; if (gids[m] < g + 1) lo = m + 1; else hi = m; }
    int cnt = lo - first;
    out[g] = pooled[g] / (float)(cnt > 0 ? cnt : 1);
}

// ---------------------------------------------------------------------------
extern "C" void kernel_launch(void* const* d_in, const int* in_sizes, int n_in,
                              void* d_out, int out_size, void* d_ws, size_t ws_size,
                              hipStream_t stream) {
    const float* atom = (const float*)d_in[0];
    const float* r    = (const float*)d_in[1];
    const float* Wemb = (const float*)d_in[2];
    const float* bemb = (const float*)d_in[3];
    const float* W1   = (const float*)d_in[4];
    const float* b1   = (const float*)d_in[5];
    const float* W2   = (const float*)d_in[6];
    const float* b2   = (const float*)d_in[7];
    const int*   src  = (const int*)d_in[8];
    const int*   dst  = (const int*)d_in[9];
    const int*   gids = (const int*)d_in[10];
    float* out = (float*)d_out;

    // Workspace layout (all chunks 16B-aligned). ~92 MB total.
    char* w = (char*)d_ws;
    // -- zeroed region --
    unsigned* C      = (unsigned*)w; w += (size_t)NV * 4;        // 6.4 MB (counts -> base)
    unsigned* O      = (unsigned*)w; w += (size_t)NV * 4;        // 6.4 MB
    float*    pooled = (float*)w;    w += (size_t)NGRAPHS * 4;   // 2 KB
    size_t zero_bytes = (size_t)(w - (char*)d_ws);
    // -- scratch --
    unsigned short* token = (unsigned short*)w; w += (size_t)NEDGES * 2;  // 12.8 MB
    int*    partial = (int*)w;   w += (size_t)((VBLK + 3) & ~3) * 4;      // 25 KB
    float*  inv_in  = (float*)w; w += (size_t)NNODES * 4;
    float*  inv_out = (float*)w; w += (size_t)NNODES * 4;
    float*  hs      = (float*)w; w += (size_t)NNODES * HPAD * 4;          // 12.8 MB
    float*  sproj   = (float*)w; w += (size_t)NNODES * 4;
    float2* csr     = (float2*)w; w += (size_t)NEDGES * 8;                // 51.2 MB

    hipMemsetAsync(d_ws, 0, zero_bytes, stream);

    const int B = 256;

    k_hist<<<EBLK, B, 0, stream>>>(src, dst, C, O, token);
    k_scan_partial<<<VBLK, B, 0, stream>>>(C, partial);
    k_scan_top<<<1, 1024, 0, stream>>>(partial);
    k_base<<<VBLK, B, 0, stream>>>(C, O, partial, inv_in, inv_out);
    k_embed<<<NBLK, B, 0, stream>>>(atom, Wemb, bemb, inv_out, hs);
    k_fill<<<EBLK, B, 0, stream>>>(r, src, dst, token, C, csr);
    k_agg1<<<NBLK, B, 0, stream>>>(csr, C, hs, W1, b1, W2, inv_in, inv_out, sproj);
    k_agg2_pool<<<NBLK, B, 0, stream>>>(csr, C, sproj, inv_in, b2, gids, pooled);
    k_final<<<(NGRAPHS + B - 1) / B, B, 0, stream>>>(pooled, gids, out);
}

// Round 5
// 895.620 us; speedup vs baseline: 1.5476x; 1.5476x over previous
//
#include <hip/hip_runtime.h>
#include <math.h>

#define NNODES  200000
#define NEDGES  6400000
#define NGRAPHS 512
#define FIN     92
#define WID     10
#define HPAD    16                     // hs row padded to 16 floats (64 B)
#define NBLK    ((NNODES + 255) / 256) // 782

// partition geometry
#define LBITS   10
#define LSIZE   1024                   // nodes per bucket
#define LMASK   (LSIZE - 1)
#define NB      196                    // ceil(200000/1024)
#define PBLK    1024                   // partition blocks
#define EPB     (NEDGES / PBLK)        // 6250 edges per partition block (exact)
#define CNT_N   (2 * NB * PBLK)        // 401,408 scan elements (dst plane, src plane)
#define SBLKS   (CNT_N / 256)          // 1568 scan blocks (exact)

// ---------------------------------------------------------------------------
// P1: per-(bucket,block) counts via LDS histograms. ZERO global atomics.
//   cnt[0*NB*PBLK + b*PBLK + k] = #edges in block k with dst>>10 == b
//   cnt[1*NB*PBLK + b*PBLK + k] = #edges in block k with src>>10 == b
// (k-inner layout => flat exclusive scan yields bucket-contiguous offsets)
// ---------------------------------------------------------------------------
__global__ void k_part_count(const int* __restrict__ src,
                             const int* __restrict__ dst,
                             int* __restrict__ cnt) {
    __shared__ int hD[NB];
    __shared__ int hS[NB];
    int tid = threadIdx.x, k = blockIdx.x;
    if (tid < NB) { hD[tid] = 0; hS[tid] = 0; }
    __syncthreads();
    int base = k * EPB;
    for (int i = tid; i < EPB; i += 256) {
        int e = base + i;
        atomicAdd(&hD[dst[e] >> LBITS], 1);
        atomicAdd(&hS[src[e] >> LBITS], 1);
    }
    __syncthreads();
    if (tid < NB) {
        cnt[tid * PBLK + k] = hD[tid];
        cnt[NB * PBLK + tid * PBLK + k] = hS[tid];
    }
}

// ---------------------------------------------------------------------------
// Scan step 1: per-block (256-elem) partial sums of cnt
// ---------------------------------------------------------------------------
__global__ void k_scan_partial(const int* __restrict__ cnt,
                               int* __restrict__ partial) {
    __shared__ int sdata[256];
    int tid = threadIdx.x;
    sdata[tid] = cnt[blockIdx.x * 256 + tid];
    __syncthreads();
    for (int s = 128; s > 0; s >>= 1) {
        if (tid < s) sdata[tid] += sdata[tid + s];
        __syncthreads();
    }
    if (tid == 0) partial[blockIdx.x] = sdata[0];
}

// ---------------------------------------------------------------------------
// Scan step 2: single-block exclusive scan of the 1568 partials (chunked)
// ---------------------------------------------------------------------------
__global__ void k_scan_top(int* __restrict__ partial) {
    __shared__ int buf[1024];
    __shared__ int carry_s;
    if (threadIdx.x == 0) carry_s = 0;
    __syncthreads();
    for (int base = 0; base < SBLKS; base += 1024) {
        int i = base + threadIdx.x;
        int c = carry_s;
        int orig = (i < SBLKS) ? partial[i] : 0;
        buf[threadIdx.x] = orig;
        __syncthreads();
        for (int off = 1; off < 1024; off <<= 1) {
            int t = (threadIdx.x >= off) ? buf[threadIdx.x - off] : 0;
            __syncthreads();
            buf[threadIdx.x] += t;
            __syncthreads();
        }
        if (i < SBLKS) partial[i] = buf[threadIdx.x] - orig + c;
        __syncthreads();
        if (threadIdx.x == 0) carry_s = c + buf[1023];
        __syncthreads();
    }
}

// ---------------------------------------------------------------------------
// Scan step 3: apply -- in-place exclusive scan of cnt (256/block + partial)
// ---------------------------------------------------------------------------
__global__ void k_scan_apply(int* __restrict__ cnt,
                             const int* __restrict__ partial) {
    __shared__ int buf[256];
    int tid = threadIdx.x;
    int i = blockIdx.x * 256 + tid;
    int v = cnt[i];
    buf[tid] = v;
    __syncthreads();
    for (int off = 1; off < 256; off <<= 1) {
        int t = (tid >= off) ? buf[tid - off] : 0;
        __syncthreads();
        buf[tid] += t;
        __syncthreads();
    }
    cnt[i] = buf[tid] - v + partial[blockIdx.x];
}

// ---------------------------------------------------------------------------
// P2: scatter edges into bucket partitions. LDS cursors seeded from the
// scanned bases give each edge a unique global slot -- ZERO global atomics.
//   dstpart[pos] = (w, src<<10 | dst&1023)   (8 B)
//   srcpart[pos] = src & 1023                (2 B, for out-degree histogram)
// ---------------------------------------------------------------------------
__global__ void k_part_scatter(const float* __restrict__ r,
                               const int* __restrict__ src,
                               const int* __restrict__ dst,
                               const int* __restrict__ cnt,
                               float2* __restrict__ dstpart,
                               unsigned short* __restrict__ srcpart) {
    __shared__ int curD[NB];
    __shared__ int curS[NB];
    int tid = threadIdx.x, k = blockIdx.x;
    if (tid < NB) {
        curD[tid] = cnt[tid * PBLK + k];
        curS[tid] = cnt[NB * PBLK + tid * PBLK + k] - NEDGES;
    }
    __syncthreads();
    int base = k * EPB;
    for (int i = tid; i < EPB; i += 256) {
        int e = base + i;
        float x = r[3 * e + 0];
        float y = r[3 * e + 1];
        float z = r[3 * e + 2];
        float w = expf(-(x * x + y * y + z * z));
        int s = src[e];
        int d = dst[e];
        int pd = atomicAdd(&curD[d >> LBITS], 1);
        dstpart[pd] = make_float2(w, __int_as_float((s << LBITS) | (d & LMASK)));
        int ps = atomicAdd(&curS[s >> LBITS], 1);
        srcpart[ps] = (unsigned short)(s & LMASK);
    }
}

// ---------------------------------------------------------------------------
// P3s: per-bucket out-degree histogram (LDS) -> inv_sqrt_out.
// Runs BEFORE k_bucket_csr because srcpart aliases the csr region.
// ---------------------------------------------------------------------------
__global__ void k_bucket_odeg(const unsigned short* __restrict__ srcpart,
                              const int* __restrict__ cnt,
                              float* __restrict__ inv_out) {
    __shared__ int hist[LSIZE];
    int tid = threadIdx.x, b = blockIdx.x;
    int bstart = cnt[NB * PBLK + b * PBLK] - NEDGES;
    int bend = (b == NB - 1) ? NEDGES : (cnt[NB * PBLK + (b + 1) * PBLK] - NEDGES);
    for (int l = tid; l < LSIZE; l += 256) hist[l] = 0;
    __syncthreads();
    for (int p = bstart + tid; p < bend; p += 256)
        atomicAdd(&hist[srcpart[p]], 1);
    __syncthreads();
    for (int l = tid; l < LSIZE; l += 256) {
        int n = (b << LBITS) + l;
        if (n < NNODES) {
            int c = hist[l];
            inv_out[n] = rsqrtf((float)(c < 1 ? 1 : c));
        }
    }
}

// ---------------------------------------------------------------------------
// P3d: per-bucket exact CSR build. LDS hist over the 1024-node range ->
// LDS scan -> row_ptr / inv_sqrt_in -> cursor placement into node-sorted csr.
// ---------------------------------------------------------------------------
__global__ void k_bucket_csr(const float2* __restrict__ dstpart,
                             const int* __restrict__ cnt,
                             float2* __restrict__ csr,
                             int* __restrict__ row_ptr,
                             float* __restrict__ inv_in) {
    __shared__ int hist[LSIZE];
    __shared__ int offl[LSIZE];
    __shared__ int sbuf[256];
    int tid = threadIdx.x, b = blockIdx.x;
    int bstart = cnt[b * PBLK];
    int bend = (b == NB - 1) ? NEDGES : cnt[(b + 1) * PBLK];

    for (int l = tid; l < LSIZE; l += 256) hist[l] = 0;
    __syncthreads();
    for (int p = bstart + tid; p < bend; p += 256) {
        float2 rec = dstpart[p];
        atomicAdd(&hist[__float_as_uint(rec.y) & LMASK], 1);
    }
    __syncthreads();

    // exclusive scan of the 1024 counters (4 per thread + block scan)
    int t4 = tid * 4;
    int h0 = hist[t4], h1 = hist[t4 + 1], h2 = hist[t4 + 2], h3 = hist[t4 + 3];
    int tot = h0 + h1 + h2 + h3;
    sbuf[tid] = tot;
    __syncthreads();
    for (int off = 1; off < 256; off <<= 1) {
        int t = (tid >= off) ? sbuf[tid - off] : 0;
        __syncthreads();
        sbuf[tid] += t;
        __syncthreads();
    }
    int ex = sbuf[tid] - tot;
    offl[t4] = ex;
    offl[t4 + 1] = ex + h0;
    offl[t4 + 2] = ex + h0 + h1;
    offl[t4 + 3] = ex + h0 + h1 + h2;
    __syncthreads();

    // row_ptr, inv_in; convert hist -> global cursor
    for (int l = tid; l < LSIZE; l += 256) {
        int c = hist[l];
        int rp = bstart + offl[l];
        int n = (b << LBITS) + l;
        if (n < NNODES) {
            row_ptr[n] = rp;
            inv_in[n] = rsqrtf((float)(c < 1 ? 1 : c));
        }
        hist[l] = rp;  // cursor (each l owned by exactly one thread here)
    }
    __syncthreads();

    // placement pass
    for (int p = bstart + tid; p < bend; p += 256) {
        float2 rec = dstpart[p];
        unsigned pk = __float_as_uint(rec.y);
        int pos = atomicAdd(&hist[pk & LMASK], 1);
        csr[pos] = make_float2(rec.x, __int_as_float((int)(pk >> LBITS)));
    }
}

// ---------------------------------------------------------------------------
// K5: hs[n,:] = (A[n,:] @ W_emb + b_emb) * inv_sqrt_out[n], padded rows
// ---------------------------------------------------------------------------
__global__ void k_embed(const float* __restrict__ A,
                        const float* __restrict__ Wemb,
                        const float* __restrict__ bemb,
                        const float* __restrict__ inv_out,
                        float* __restrict__ hs) {
    __shared__ float sW[FIN * WID];
    __shared__ float sb[WID];
    for (int i = threadIdx.x; i < FIN * WID; i += blockDim.x) sW[i] = Wemb[i];
    if (threadIdx.x < WID) sb[threadIdx.x] = bemb[threadIdx.x];
    __syncthreads();

    int n = blockIdx.x * blockDim.x + threadIdx.x;
    if (n >= NNODES) return;

    float acc[WID];
#pragma unroll
    for (int k = 0; k < WID; k++) acc[k] = sb[k];

    const float4* row4 = reinterpret_cast<const float4*>(A + (size_t)n * FIN);
#pragma unroll
    for (int f4 = 0; f4 < FIN / 4; f4++) {
        float4 v = row4[f4];
        int f = f4 * 4;
#pragma unroll
        for (int k = 0; k < WID; k++) acc[k] += v.x * sW[(f + 0) * WID + k];
#pragma unroll
        for (int k = 0; k < WID; k++) acc[k] += v.y * sW[(f + 1) * WID + k];
#pragma unroll
        for (int k = 0; k < WID; k++) acc[k] += v.z * sW[(f + 2) * WID + k];
#pragma unroll
        for (int k = 0; k < WID; k++) acc[k] += v.w * sW[(f + 3) * WID + k];
    }

    float sc = inv_out[n];
    float* out = hs + (size_t)n * HPAD;
    float4 o0 = make_float4(acc[0] * sc, acc[1] * sc, acc[2] * sc, acc[3] * sc);
    float4 o1 = make_float4(acc[4] * sc, acc[5] * sc, acc[6] * sc, acc[7] * sc);
    float2 o2 = make_float2(acc[8] * sc, acc[9] * sc);
    *reinterpret_cast<float4*>(out + 0) = o0;
    *reinterpret_cast<float4*>(out + 4) = o1;
    *reinterpret_cast<float2*>(out + 8) = o2;
}

// ---------------------------------------------------------------------------
// K7: pull-mode aggregate of gconv1 FUSED with node update + gconv2 proj
// ---------------------------------------------------------------------------
__global__ void k_agg1(const float2* __restrict__ csr,
                       const int* __restrict__ row_ptr,
                       const float* __restrict__ hs,
                       const float* __restrict__ W1,
                       const float* __restrict__ b1,
                       const float* __restrict__ W2,
                       const float* __restrict__ inv_in,
                       const float* __restrict__ inv_out,
                       float* __restrict__ sproj) {
    __shared__ float sW1[WID * WID];
    __shared__ float sb1[WID];
    __shared__ float sW2[WID];
    for (int i = threadIdx.x; i < WID * WID; i += blockDim.x) sW1[i] = W1[i];
    if (threadIdx.x < WID) {
        sb1[threadIdx.x] = b1[threadIdx.x];
        sW2[threadIdx.x] = W2[threadIdx.x];
    }
    __syncthreads();

    int n = blockIdx.x * blockDim.x + threadIdx.x;
    if (n >= NNODES) return;

    int start = row_ptr[n];
    int end = (n == NNODES - 1) ? NEDGES : row_ptr[n + 1];

    float acc[WID];
#pragma unroll
    for (int k = 0; k < WID; k++) acc[k] = 0.0f;

    for (int p = start; p < end; p++) {
        float2 c2 = csr[p];
        float w = c2.x;
        int s = __float_as_int(c2.y);
        const float* hrow = hs + (size_t)s * HPAD;
        float4 a = *reinterpret_cast<const float4*>(hrow + 0);
        float4 b = *reinterpret_cast<const float4*>(hrow + 4);
        float2 c = *reinterpret_cast<const float2*>(hrow + 8);
        acc[0] += w * a.x; acc[1] += w * a.y; acc[2] += w * a.z; acc[3] += w * a.w;
        acc[4] += w * b.x; acc[5] += w * b.y; acc[6] += w * b.z; acc[7] += w * b.w;
        acc[8] += w * c.x; acc[9] += w * c.y;
    }

    float ii = inv_in[n];
    float dot = 0.0f;
#pragma unroll
    for (int j = 0; j < WID; j++) {
        float y = 0.0f;
#pragma unroll
        for (int k = 0; k < WID; k++) y += acc[k] * sW1[k * WID + j];
        y = y * ii + sb1[j];
        y = y > 0.0f ? y : 0.0f;
        dot += y * sW2[j];
    }
    sproj[n] = dot * inv_out[n];
}

// ---------------------------------------------------------------------------
// K8: pull-mode scalar aggregate of gconv2 FUSED with graph pooling.
// NOTE: __shfl_down clamps out-of-range lanes to SELF on AMD -> guard with
// lane + off < 64 (round-2 bug).
// ---------------------------------------------------------------------------
__global__ void k_agg2_pool(const float2* __restrict__ csr,
                            const int* __restrict__ row_ptr,
                            const float* __restrict__ sproj,
                            const float* __restrict__ inv_in,
                            const float* __restrict__ b2,
                            const int* __restrict__ graph_ids,
                            float* __restrict__ pooled) {
    int n = blockIdx.x * blockDim.x + threadIdx.x;
    int lane = threadIdx.x & 63;

    float v = 0.0f;
    int g = -1;
    if (n < NNODES) {
        int start = row_ptr[n];
        int end = (n == NNODES - 1) ? NEDGES : row_ptr[n + 1];
        float sum = 0.0f;
        for (int p = start; p < end; p++) {
            float2 c2 = csr[p];
            sum += c2.x * sproj[__float_as_int(c2.y)];
        }
        v = sum * inv_in[n] + b2[0];
        g = graph_ids[n];
    }

#pragma unroll
    for (int off = 1; off < 64; off <<= 1) {
        float vv = __shfl_down(v, off, 64);
        int gg = __shfl_down(g, off, 64);
        if (lane + off < 64 && gg == g) v += vv;
    }
    int gprev = __shfl_up(g, 1, 64);
    bool head = (lane == 0) || (gprev != g);
    if (g >= 0 && head) atomicAdd(&pooled[g], v);
}

// ---------------------------------------------------------------------------
// K9: out[g] = pooled[g] / count(g); counts via binary search on sorted gids
// ---------------------------------------------------------------------------
__global__ void k_final(const float* __restrict__ pooled,
                        const int* __restrict__ gids,
                        float* __restrict__ out) {
    int g = blockIdx.x * blockDim.x + threadIdx.x;
    if (g >= NGRAPHS) return;
    int lo = 0, hi = NNODES;
    while (lo < hi) { int m = (lo + hi) >> 1; if (gids[m] < g) lo = m + 1; else hi = m; }
    int first = lo;
    hi = NNODES;
    while (lo < hi) { int m = (lo + hi) >> 1; if (gids[m] < g + 1) lo = m + 1; else hi = m; }
    int cnt = lo - first;
    out[g] = pooled[g] / (float)(cnt > 0 ? cnt : 1);
}

// ---------------------------------------------------------------------------
extern "C" void kernel_launch(void* const* d_in, const int* in_sizes, int n_in,
                              void* d_out, int out_size, void* d_ws, size_t ws_size,
                              hipStream_t stream) {
    const float* atom = (const float*)d_in[0];
    const float* r    = (const float*)d_in[1];
    const float* Wemb = (const float*)d_in[2];
    const float* bemb = (const float*)d_in[3];
    const float* W1   = (const float*)d_in[4];
    const float* b1   = (const float*)d_in[5];
    const float* W2   = (const float*)d_in[6];
    const float* b2   = (const float*)d_in[7];
    const int*   src  = (const int*)d_in[8];
    const int*   dst  = (const int*)d_in[9];
    const int*   gids = (const int*)d_in[10];
    float* out = (float*)d_out;

    // Workspace layout (16B-aligned chunks), ~120 MB total.
    char* w = (char*)d_ws;
    float* pooled  = (float*)w;  w += (size_t)NGRAPHS * 4;          // zeroed (2 KB)
    int*   cnt     = (int*)w;    w += (size_t)CNT_N * 4;            // 1.6 MB
    int*   partial = (int*)w;    w += (size_t)((SBLKS + 3) & ~3) * 4;
    int*   row_ptr = (int*)w;    w += (size_t)((NNODES + 4) & ~3) * 4;
    float* inv_in  = (float*)w;  w += (size_t)NNODES * 4;
    float* inv_out = (float*)w;  w += (size_t)NNODES * 4;
    float* sproj   = (float*)w;  w += (size_t)NNODES * 4;
    float* hs      = (float*)w;  w += (size_t)NNODES * HPAD * 4;    // 12.8 MB
    float2* dstpart = (float2*)w; w += (size_t)NEDGES * 8;          // 51.2 MB
    float2* csr     = (float2*)w; w += (size_t)NEDGES * 8;          // 51.2 MB
    // srcpart aliases csr: dead before k_bucket_csr writes csr
    unsigned short* srcpart = (unsigned short*)csr;                 // 12.8 MB view

    hipMemsetAsync(pooled, 0, (size_t)NGRAPHS * 4, stream);

    const int B = 256;

    k_part_count<<<PBLK, B, 0, stream>>>(src, dst, cnt);
    k_scan_partial<<<SBLKS, B, 0, stream>>>(cnt, partial);
    k_scan_top<<<1, 1024, 0, stream>>>(partial);
    k_scan_apply<<<SBLKS, B, 0, stream>>>(cnt, partial);
    k_part_scatter<<<PBLK, B, 0, stream>>>(r, src, dst, cnt, dstpart, srcpart);
    k_bucket_odeg<<<NB, B, 0, stream>>>(srcpart, cnt, inv_out);   // before csr write (alias)
    k_bucket_csr<<<NB, B, 0, stream>>>(dstpart, cnt, csr, row_ptr, inv_in);
    k_embed<<<NBLK, B, 0, stream>>>(atom, Wemb, bemb, inv_out, hs);
    k_agg1<<<NBLK, B, 0, stream>>>(csr, row_ptr, hs, W1, b1, W2, inv_in, inv_out, sproj);
    k_agg2_pool<<<NBLK, B, 0, stream>>>(csr, row_ptr, sproj, inv_in, b2, gids, pooled);
    k_final<<<(NGRAPHS + B - 1) / B, B, 0, stream>>>(pooled, gids, out);
}